// Round 7
// baseline (66.138 us; speedup 1.0000x reference)
//
#include <hip/hip_runtime.h>
#include <hip/hip_bf16.h>

// AWQ 4-bit linear: out[32,11008] = x[32,4096] @ ((q - z)*s) + bias
// ROUND 7 = ATTRIBUTION ROUND. Kernels are byte-identical to round 6
// (32.4 us). awq_main is launched 3x (idempotent: same values to same ws
// slabs; reduce runs last -> output identical). dur7 = dur6 + 2*main, so
//   main  = (dur7 - 32.4) / 2
//   reduce ~= 32.4 - main - xconv(~1us)
// This splits the 32.4 us between awq_main and awq_reduce, which rocprof
// top-5 cannot show (harness 256MB ws-poison fills dominate the table).

#define IN_F   4096
#define OUT_F  11008
#define WCOLS  1376
#define NCOLB  86                 // 11008/128
#define KSPLIT 16
#define CHUNK  (IN_F/KSPLIT)      // 256
#define NTILE  (CHUNK/32)         // 8
#define NBLK   (NCOLB*KSPLIT)     // 1376
#define MROWS  32
#define SLAB   (MROWS*OUT_F)      // floats per k-partial slab (352256)

typedef __attribute__((ext_vector_type(8))) short  short8;
typedef __attribute__((ext_vector_type(4))) short  short4v;
typedef __attribute__((ext_vector_type(4))) float  f32x4;
typedef __attribute__((ext_vector_type(4))) int    int4v;

__device__ __forceinline__ short f2bf(float f) {
  return (short)__builtin_bit_cast(unsigned short, (__bf16)f);
}
__device__ __forceinline__ f32x4 mfma16(short8 a, short8 b, f32x4 c) {
  return __builtin_amdgcn_mfma_f32_16x16x32_bf16(a, b, c, 0, 0, 0);
}

__global__ void awq_init(const float* __restrict__ bias, float* __restrict__ out) {
  int o = blockIdx.x * 256 + threadIdx.x;
  out[blockIdx.y * OUT_F + o] = bias[o];
}

__global__ void xconv(const float* __restrict__ x, unsigned short* __restrict__ xb) {
  int i = blockIdx.x * 256 + threadIdx.x;          // 128 blocks -> 32768 f32x4
  f32x4 v = ((const f32x4*)x)[i];
  short4v o;
  #pragma unroll
  for (int j = 0; j < 4; ++j) o[j] = f2bf(v[j]);
  ((short4v*)xb)[i] = o;
}

__global__ __launch_bounds__(256) void awq_reduce(
    const float* __restrict__ ws, const float* __restrict__ bias,
    float* __restrict__ out)
{
  const int i = blockIdx.x * 256 + threadIdx.x;    // f32x4 id, 88064 total
  const f32x4* w4 = (const f32x4*)ws;
  f32x4 s = w4[i];
  #pragma unroll
  for (int k = 1; k < KSPLIT; ++k) s += w4[k * (SLAB / 4) + i];
  const f32x4 b = *(const f32x4*)(bias + (i % (OUT_F / 4)) * 4);
  ((f32x4*)out)[i] = s + b;
}

template<bool PRE, bool TOWS>
__global__ __launch_bounds__(256, 4) void awq_main(
    const float* __restrict__ x, const unsigned short* __restrict__ xb,
    const int* __restrict__ qw, const int* __restrict__ qz,
    const float* __restrict__ sc, float* __restrict__ outp)
{
  // [col 0..127][k-pair 0..15] dwords, double-buffered: 2 x 8KB.
  __shared__ int lds[2][2048];

  const int tid  = threadIdx.x;
  const int w    = tid >> 6;           // wave -> 32-col subtile
  const int lane = tid & 63;
  const int q4   = lane >> 4;

  // Bijective XCD swizzle (1376 = 8*172)
  const int b  = blockIdx.x;
  const int L  = (b & 7) * (NBLK / 8) + (b >> 3);
  const int colblk = L % NCOLB;
  const int kchunk = L / NCOLB;

  const int cb  = colblk * 128;        // first output column
  const int wcb = colblk * 16;         // first packed word
  const int K0  = kchunk * CHUNK;
  const int g0  = kchunk * (CHUNK / 128);

  const int wr = tid & 15;             // word within block -> cols 8wr..8wr+7
  const int kp = tid >> 4;             // k-pair 0..15 -> k = 2kp, 2kp+1

  float s8[8], zs8[8];
  auto load_group = [&](int g) {
    const f32x4 sa = *(const f32x4*)(sc + g * OUT_F + cb + 8 * wr);
    const f32x4 sb = *(const f32x4*)(sc + g * OUT_F + cb + 8 * wr + 4);
    const int   zw = qz[g * WCOLS + wcb + wr];
    #pragma unroll
    for (int j = 0; j < 8; ++j) {
      const int sh = 4 * (j >> 1) + 16 * (j & 1);   // shift = 4*REV[j]
      const float sv = (j < 4) ? sa[j] : sb[j - 4];
      s8[j]  = sv;
      zs8[j] = -(float)((zw >> sh) & 15) * sv;
    }
  };
  auto load_q = [&](int t, int& q0, int& q1) {
    const int r = (K0 + t * 32 + 2 * kp) * WCOLS + wcb + wr;
    q0 = qw[r];
    q1 = qw[r + WCOLS];
  };
  auto load_a = [&](int t, int mf) -> short8 {
    const int m = (lane & 15) + 16 * mf;
    const int k = K0 + t * 32 + q4 * 8;
    if constexpr (PRE) {
      return *(const short8*)(xb + m * IN_F + k);
    } else {
      const f32x4* xp = (const f32x4*)(x + m * IN_F + k);
      f32x4 lo = xp[0], hi = xp[1];
      short8 af;
      #pragma unroll
      for (int j = 0; j < 4; ++j) { af[j] = f2bf(lo[j]); af[4 + j] = f2bf(hi[j]); }
      return af;
    }
  };
  auto read_b = [&](int p, int c) -> short8 {
    const int idx = c * 16 + 4 * (q4 ^ ((c >> 3) & 3));   // 16B-aligned
    return __builtin_bit_cast(short8, *(const int4v*)&lds[p][idx]);
  };

  // ---- prologue
  load_group(g0);
  int q0c, q1c; load_q(0, q0c, q1c);
  f32x4 acc[2][2] = {};

  #pragma unroll 2
  for (int t = 0; t < NTILE; ++t) {
    // A-fragments issued early; dequant VALU hides their (L1/L2-hot) latency.
    short8 a0 = load_a(t, 0), a1 = load_a(t, 1);
    int q0n = 0, q1n = 0;
    if (t + 1 < NTILE) load_q(t + 1, q0n, q1n);   // prefetch next q tile
    if (t == 4) load_group(g0 + 1);               // tiles 4..7: second group

    // dequant 16 nibbles -> 8 packed bf16x2 -> LDS [col][k] (swizzled k-pair)
    const int p = t & 1;
    const int kps = kp ^ ((wr & 3) << 2);
    #pragma unroll
    for (int j = 0; j < 8; ++j) {
      const int sh = 4 * (j >> 1) + 16 * (j & 1);
      const float lo = fmaf((float)((q0c >> sh) & 15), s8[j], zs8[j]);
      const float hi = fmaf((float)((q1c >> sh) & 15), s8[j], zs8[j]);
      const unsigned int pk =
          (unsigned int)(unsigned short)__builtin_bit_cast(unsigned short, (__bf16)lo) |
          ((unsigned int)(unsigned short)__builtin_bit_cast(unsigned short, (__bf16)hi) << 16);
      lds[p][(8 * wr + j) * 16 + kps] = (int)pk;
    }
    __syncthreads();

    const int c0 = w * 32 + (lane & 15);
    short8 bf0 = read_b(p, c0);
    short8 bf1 = read_b(p, c0 + 16);

    acc[0][0] = mfma16(a0, bf0, acc[0][0]);
    acc[0][1] = mfma16(a0, bf1, acc[0][1]);
    acc[1][0] = mfma16(a1, bf0, acc[1][0]);
    acc[1][1] = mfma16(a1, bf1, acc[1][1]);

    q0c = q0n; q1c = q1n;
  }

  // ---- epilogue
  const int col0 = cb + w * 32 + (lane & 15);
  const int r0 = q4 * 4;
  if constexpr (TOWS) {
    // plain stores to this k-chunk's private partial slab
    float* wsp = outp + kchunk * SLAB;
    #pragma unroll
    for (int mf = 0; mf < 2; ++mf) {
      #pragma unroll
      for (int i = 0; i < 4; ++i) {
        const int row = mf * 16 + r0 + i;
        wsp[row * OUT_F + col0]      = acc[mf][0][i];
        wsp[row * OUT_F + col0 + 16] = acc[mf][1][i];
      }
    }
  } else {
    // fallback: fp32 atomics onto bias-initialized out
    #pragma unroll
    for (int mf = 0; mf < 2; ++mf) {
      #pragma unroll
      for (int i = 0; i < 4; ++i) {
        const int row = mf * 16 + r0 + i;
        atomicAdd(outp + row * OUT_F + col0,      acc[mf][0][i]);
        atomicAdd(outp + row * OUT_F + col0 + 16, acc[mf][1][i]);
      }
    }
  }
}

extern "C" void kernel_launch(void* const* d_in, const int* in_sizes, int n_in,
                              void* d_out, int out_size, void* d_ws, size_t ws_size,
                              hipStream_t stream) {
  const float* x    = (const float*)d_in[0];
  const int*   qwp  = (const int*)d_in[1];
  const int*   qzp  = (const int*)d_in[2];
  const float* scp  = (const float*)d_in[3];
  const float* bias = (const float*)d_in[4];
  float* out = (float*)d_out;

  const size_t ws_part = (size_t)KSPLIT * SLAB * sizeof(float);   // 22.5 MB
  const size_t xb_sz   = (size_t)MROWS * IN_F * 2;                // 256 KB

  if (ws_size >= ws_part + xb_sz) {
    float* ws = (float*)d_ws;
    unsigned short* xb = (unsigned short*)((char*)d_ws + ws_part);
    xconv<<<128, 256, 0, stream>>>(x, xb);
    // ATTRIBUTION: 3 idempotent launches of the identical main kernel.
    // dur7 - dur6 = 2 * t(awq_main). Output unchanged.
    awq_main<true, true><<<NBLK, 256, 0, stream>>>(x, xb, qwp, qzp, scp, ws);
    awq_main<true, true><<<NBLK, 256, 0, stream>>>(x, xb, qwp, qzp, scp, ws);
    awq_main<true, true><<<NBLK, 256, 0, stream>>>(x, xb, qwp, qzp, scp, ws);
    awq_reduce<<<SLAB / 4 / 256, 256, 0, stream>>>(ws, bias, out);
  } else {
    awq_init<<<dim3(43, 32), 256, 0, stream>>>(bias, out);
    awq_main<false, false><<<NBLK, 256, 0, stream>>>(x, nullptr, qwp, qzp, scp, out);
  }
}

// Round 8
// 31.509 us; speedup vs baseline: 2.0990x; 2.0990x over previous
//
#include <hip/hip_runtime.h>
#include <hip/hip_bf16.h>

// AWQ 4-bit linear: out[32,11008] = x[32,4096] @ ((q - z)*s) + bias
// BN=128 col-block, BK=32 k-tiles, dequant->LDS [col][k] (XOR-swizzled
// k-pair), B-fragment = ds_read_b128, double-buffered, 1 barrier/tile.
// Round 8 (from round-7 attribution: main=16.9us, reduce~13us):
//  - q prefetch ring depth 3 (named regs, static rotation) -> enough
//    bytes in flight to make the qw stream BW-bound, not latency-bound.
//  - KSPLIT 16->8: halves slab round-trip (22.5->11.25 MB each way).
//  - group scale/zero raws prefetched 2 tiles before use.

#define IN_F   4096
#define OUT_F  11008
#define WCOLS  1376
#define NCOLB  86                 // 11008/128
#define KSPLIT 8
#define CHUNK  (IN_F/KSPLIT)      // 512
#define NTILE  (CHUNK/32)         // 16
#define NBLK   (NCOLB*KSPLIT)     // 688
#define MROWS  32
#define SLAB   (MROWS*OUT_F)      // floats per k-partial slab (352256)

typedef __attribute__((ext_vector_type(8))) short  short8;
typedef __attribute__((ext_vector_type(4))) short  short4v;
typedef __attribute__((ext_vector_type(4))) float  f32x4;
typedef __attribute__((ext_vector_type(4))) int    int4v;

__device__ __forceinline__ short f2bf(float f) {
  return (short)__builtin_bit_cast(unsigned short, (__bf16)f);
}
__device__ __forceinline__ f32x4 mfma16(short8 a, short8 b, f32x4 c) {
  return __builtin_amdgcn_mfma_f32_16x16x32_bf16(a, b, c, 0, 0, 0);
}

__global__ void awq_init(const float* __restrict__ bias, float* __restrict__ out) {
  int o = blockIdx.x * 256 + threadIdx.x;
  out[blockIdx.y * OUT_F + o] = bias[o];
}

__global__ void xconv(const float* __restrict__ x, unsigned short* __restrict__ xb) {
  int i = blockIdx.x * 256 + threadIdx.x;          // 128 blocks -> 32768 f32x4
  f32x4 v = ((const f32x4*)x)[i];
  short4v o;
  #pragma unroll
  for (int j = 0; j < 4; ++j) o[j] = f2bf(v[j]);
  ((short4v*)xb)[i] = o;
}

__global__ __launch_bounds__(256) void awq_reduce(
    const float* __restrict__ ws, const float* __restrict__ bias,
    float* __restrict__ out)
{
  const int i = blockIdx.x * 256 + threadIdx.x;    // f32x4 id, 88064 total
  const f32x4* w4 = (const f32x4*)ws;
  f32x4 s = w4[i];
  #pragma unroll
  for (int k = 1; k < KSPLIT; ++k) s += w4[k * (SLAB / 4) + i];
  const f32x4 b = *(const f32x4*)(bias + (i % (OUT_F / 4)) * 4);
  ((f32x4*)out)[i] = s + b;
}

template<bool PRE, bool TOWS>
__global__ __launch_bounds__(256, 4) void awq_main(
    const float* __restrict__ x, const unsigned short* __restrict__ xb,
    const int* __restrict__ qw, const int* __restrict__ qz,
    const float* __restrict__ sc, float* __restrict__ outp)
{
  // [col 0..127][k-pair 0..15] dwords, double-buffered: 2 x 8KB.
  __shared__ int lds[2][2048];

  const int tid  = threadIdx.x;
  const int w    = tid >> 6;           // wave -> 32-col subtile
  const int lane = tid & 63;
  const int q4   = lane >> 4;

  // Bijective XCD swizzle (688 = 8*86)
  const int b  = blockIdx.x;
  const int L  = (b & 7) * (NBLK / 8) + (b >> 3);
  const int colblk = L % NCOLB;
  const int kchunk = L / NCOLB;

  const int cb  = colblk * 128;        // first output column
  const int wcb = colblk * 16;         // first packed word
  const int K0  = kchunk * CHUNK;
  const int g0  = kchunk * (CHUNK / 128);   // 4 groups per chunk

  const int wr = tid & 15;             // word within block -> cols 8wr..8wr+7
  const int kp = tid >> 4;             // k-pair 0..15 -> k = 2kp, 2kp+1

  // group scale/zero staging: raw (prefetched) -> converted s8/zs8
  f32x4 sra, srb; int zrw;
  float s8[8], zs8[8];
  auto load_group_raw = [&](int g) {
    sra = *(const f32x4*)(sc + g * OUT_F + cb + 8 * wr);
    srb = *(const f32x4*)(sc + g * OUT_F + cb + 8 * wr + 4);
    zrw = qz[g * WCOLS + wcb + wr];
  };
  auto conv_group = [&]() {
    #pragma unroll
    for (int j = 0; j < 8; ++j) {
      const int sh = 4 * (j >> 1) + 16 * (j & 1);   // shift = 4*REV[j]
      const float sv = (j < 4) ? sra[j] : srb[j - 4];
      s8[j]  = sv;
      zs8[j] = -(float)((zrw >> sh) & 15) * sv;
    }
  };
  auto load_q = [&](int t, int& q0, int& q1) {
    const int r = (K0 + t * 32 + 2 * kp) * WCOLS + wcb + wr;
    q0 = qw[r];
    q1 = qw[r + WCOLS];
  };
  auto load_a = [&](int t, int mf) -> short8 {
    const int m = (lane & 15) + 16 * mf;
    const int k = K0 + t * 32 + q4 * 8;
    if constexpr (PRE) {
      return *(const short8*)(xb + m * IN_F + k);
    } else {
      const f32x4* xp = (const f32x4*)(x + m * IN_F + k);
      f32x4 lo = xp[0], hi = xp[1];
      short8 af;
      #pragma unroll
      for (int j = 0; j < 4; ++j) { af[j] = f2bf(lo[j]); af[4 + j] = f2bf(hi[j]); }
      return af;
    }
  };
  auto read_b = [&](int p, int c) -> short8 {
    const int idx = c * 16 + 4 * (q4 ^ ((c >> 3) & 3));   // 16B-aligned
    return __builtin_bit_cast(short8, *(const int4v*)&lds[p][idx]);
  };

  // ---- prologue: group raws + q prefetch ring (depth 3, named regs)
  load_group_raw(g0);
  conv_group();
  int q0a, q1a, q0b, q1b, q0c, q1c;
  load_q(0, q0a, q1a);
  load_q(1, q0b, q1b);
  load_q(2, q0c, q1c);
  f32x4 acc[2][2] = {};

  #pragma unroll 4
  for (int t = 0; t < NTILE; ++t) {
    short8 a0 = load_a(t, 0), a1 = load_a(t, 1);
    int q0n = 0, q1n = 0;
    if (t + 3 < NTILE) load_q(t + 3, q0n, q1n);            // ring refill
    if ((t & 3) == 2 && (t >> 2) + 1 < CHUNK / 128)
      load_group_raw(g0 + (t >> 2) + 1);                   // raw 2 tiles early
    if ((t & 3) == 0 && t > 0) conv_group();               // group t>>2 live

    // dequant 16 nibbles -> 8 packed bf16x2 -> LDS [col][k] (swizzled k-pair)
    const int p = t & 1;
    const int kps = kp ^ ((wr & 3) << 2);
    #pragma unroll
    for (int j = 0; j < 8; ++j) {
      const int sh = 4 * (j >> 1) + 16 * (j & 1);
      const float lo = fmaf((float)((q0a >> sh) & 15), s8[j], zs8[j]);
      const float hi = fmaf((float)((q1a >> sh) & 15), s8[j], zs8[j]);
      const unsigned int pk =
          (unsigned int)(unsigned short)__builtin_bit_cast(unsigned short, (__bf16)lo) |
          ((unsigned int)(unsigned short)__builtin_bit_cast(unsigned short, (__bf16)hi) << 16);
      lds[p][(8 * wr + j) * 16 + kps] = (int)pk;
    }
    __syncthreads();

    const int c0 = w * 32 + (lane & 15);
    short8 bf0 = read_b(p, c0);
    short8 bf1 = read_b(p, c0 + 16);

    acc[0][0] = mfma16(a0, bf0, acc[0][0]);
    acc[0][1] = mfma16(a0, bf1, acc[0][1]);
    acc[1][0] = mfma16(a1, bf0, acc[1][0]);
    acc[1][1] = mfma16(a1, bf1, acc[1][1]);

    // rotate prefetch ring (static, SSA-friendly)
    q0a = q0b; q1a = q1b;
    q0b = q0c; q1b = q1c;
    q0c = q0n; q1c = q1n;
  }

  // ---- epilogue
  const int col0 = cb + w * 32 + (lane & 15);
  const int r0 = q4 * 4;
  if constexpr (TOWS) {
    float* wsp = outp + kchunk * SLAB;
    #pragma unroll
    for (int mf = 0; mf < 2; ++mf) {
      #pragma unroll
      for (int i = 0; i < 4; ++i) {
        const int row = mf * 16 + r0 + i;
        wsp[row * OUT_F + col0]      = acc[mf][0][i];
        wsp[row * OUT_F + col0 + 16] = acc[mf][1][i];
      }
    }
  } else {
    #pragma unroll
    for (int mf = 0; mf < 2; ++mf) {
      #pragma unroll
      for (int i = 0; i < 4; ++i) {
        const int row = mf * 16 + r0 + i;
        atomicAdd(outp + row * OUT_F + col0,      acc[mf][0][i]);
        atomicAdd(outp + row * OUT_F + col0 + 16, acc[mf][1][i]);
      }
    }
  }
}

extern "C" void kernel_launch(void* const* d_in, const int* in_sizes, int n_in,
                              void* d_out, int out_size, void* d_ws, size_t ws_size,
                              hipStream_t stream) {
  const float* x    = (const float*)d_in[0];
  const int*   qwp  = (const int*)d_in[1];
  const int*   qzp  = (const int*)d_in[2];
  const float* scp  = (const float*)d_in[3];
  const float* bias = (const float*)d_in[4];
  float* out = (float*)d_out;

  const size_t ws_part = (size_t)KSPLIT * SLAB * sizeof(float);   // 11.25 MB
  const size_t xb_sz   = (size_t)MROWS * IN_F * 2;                // 256 KB

  if (ws_size >= ws_part + xb_sz) {
    float* ws = (float*)d_ws;
    unsigned short* xb = (unsigned short*)((char*)d_ws + ws_part);
    xconv<<<128, 256, 0, stream>>>(x, xb);
    awq_main<true, true><<<NBLK, 256, 0, stream>>>(x, xb, qwp, qzp, scp, ws);
    awq_reduce<<<SLAB / 4 / 256, 256, 0, stream>>>(ws, bias, out);
  } else {
    awq_init<<<dim3(43, 32), 256, 0, stream>>>(bias, out);
    awq_main<false, false><<<NBLK, 256, 0, stream>>>(x, nullptr, qwp, qzp, scp, out);
  }
}